// Round 1
// baseline (752.685 us; speedup 1.0000x reference)
//
#include <hip/hip_runtime.h>
#include <hip/hip_bf16.h>
#include <stdint.h>

#define IN_DIM 256

typedef __attribute__((ext_vector_type(8))) short short8;
typedef __attribute__((ext_vector_type(4))) float f32x4;

__device__ __forceinline__ float bf2f(unsigned short u){
  unsigned int v = ((unsigned int)u) << 16;
  return __uint_as_float(v);
}
__device__ __forceinline__ unsigned short f2bf(float f){
  unsigned int u = __float_as_uint(f);
  u = u + 0x7FFFu + ((u >> 16) & 1u);
  return (unsigned short)(u >> 16);
}

// ---------------- edge dtype detection (int64 vs int32) ----------------
__global__ void k_detect(const void* ei, long long E, int N, int* flag){
  __shared__ int bad;
  if (threadIdx.x == 0) bad = 0;
  __syncthreads();
  const long long* p = (const long long*)ei;
  long long stride = E / 1024; if (stride < 1) stride = 1;
  for (int i = threadIdx.x; i < 1024; i += blockDim.x){
    long long idx = (long long)i * stride;
    if (idx >= E) break;
    long long v = p[idx];
    if (v < 0 || v >= (long long)N) atomicOr(&bad, 1);
  }
  __syncthreads();
  if (threadIdx.x == 0) flag[0] = bad ? 0 : 1;  // 1 = int64 data
}

__device__ __forceinline__ int edge_at(const void* ei, long long i, int f64){
  if (f64) return (int)((const long long*)ei)[i];
  return ((const int*)ei)[i];
}

// ---------------- CSR build ----------------
__global__ void k_hist(const void* ei, long long E, const int* flag, int* cnt){
  long long e = (long long)blockIdx.x * blockDim.x + threadIdx.x;
  if (e < E){
    int f = flag[0];
    int d = edge_at(ei, E + e, f);
    atomicAdd(&cnt[d], 1);
  }
}

__global__ void k_dinv(const int* cnt, float* dinv, int N){
  int n = blockIdx.x * blockDim.x + threadIdx.x;
  if (n < N) dinv[n] = rsqrtf((float)cnt[n] + 1.0f);
}

__global__ void k_scan1(const int* cnt, int* rs, int* bsum, int N){
  __shared__ int sh[1024];
  int i = blockIdx.x * 1024 + threadIdx.x;
  int v = (i < N) ? cnt[i] : 0;
  sh[threadIdx.x] = v;
  __syncthreads();
  for (int o = 1; o < 1024; o <<= 1){
    int x = (threadIdx.x >= o) ? sh[threadIdx.x - o] : 0;
    __syncthreads();
    sh[threadIdx.x] += x;
    __syncthreads();
  }
  if (i < N) rs[i] = sh[threadIdx.x] - v;          // exclusive
  if (threadIdx.x == 1023) bsum[blockIdx.x] = sh[1023];
}

__global__ void k_scan2(const int* bsum, int* boff, int nb, int* rs, int N){
  __shared__ int sh[128];
  int t = threadIdx.x;
  int v = (t < nb) ? bsum[t] : 0;
  sh[t] = v;
  __syncthreads();
  for (int o = 1; o < 128; o <<= 1){
    int x = (t >= o) ? sh[t - o] : 0;
    __syncthreads();
    sh[t] += x;
    __syncthreads();
  }
  boff[t] = sh[t] - v;
  if (t == 127) rs[N] = sh[127];
}

__global__ void k_scan3(int* rs, const int* boff, int N){
  int i = blockIdx.x * 1024 + threadIdx.x;
  if (i < N) rs[i] += boff[blockIdx.x];
}

__global__ void k_scatter(const void* ei, long long E, const int* flag, const int* rs,
                          int* fill, int* csrc){
  long long e = (long long)blockIdx.x * blockDim.x + threadIdx.x;
  if (e < E){
    int f = flag[0];
    int s = edge_at(ei, e, f);
    int d = edge_at(ei, E + e, f);
    int pos = atomicAdd(&fill[d], 1);
    csrc[rs[d] + pos] = s;
  }
}

// ---------------- conversions ----------------
__global__ void k_convx(const float* __restrict__ x, ushort* __restrict__ xb, int N){
  int idx = blockIdx.x * blockDim.x + threadIdx.x;   // over NP*64
  int row = idx >> 6, q = idx & 63;
  ushort4 o;
  if (row < N){
    float4 v = ((const float4*)x)[(long long)row * 64 + q];
    o.x = f2bf(v.x); o.y = f2bf(v.y); o.z = f2bf(v.z); o.w = f2bf(v.w);
  } else { o.x = 0; o.y = 0; o.z = 0; o.w = 0; }
  ((ushort4*)xb)[(long long)row * 64 + q] = o;
}

// W [K][Nc] fp32 -> Wt [Nc][K] bf16
__global__ void k_convw(const float* __restrict__ W, ushort* __restrict__ Wt, int K, int Nc){
  int idx = blockIdx.x * blockDim.x + threadIdx.x;   // Nc*K
  int n = idx / K, k = idx - n * K;
  Wt[idx] = f2bf(W[(long long)k * Nc + n]);
}

// ---------------- GEMM: C[M,Nc] = A[M,256] @ Bt[Nc,256]^T  (bf16 in, bf16 out) ----------------
__global__ __launch_bounds__(256) void k_gemm(const ushort* __restrict__ A,
                                              const ushort* __restrict__ Bt,
                                              ushort* __restrict__ C, int Nc){
  __shared__ ushort As[128 * 64];
  __shared__ ushort Bs[128 * 64];
  const int tid = threadIdx.x;
  const int wave = tid >> 6, lane = tid & 63;
  const long long row0 = (long long)blockIdx.x * 128;
  const int col0 = blockIdx.y * 128;
  const int lr = lane >> 3, lc = lane & 7;
  const int mrow = ((wave & 1) << 6) + (lane & 15);
  const int ncol = ((wave >> 1) << 6) + (lane & 15);

  f32x4 acc[4][4];
  #pragma unroll
  for (int i = 0; i < 4; ++i)
    #pragma unroll
    for (int j = 0; j < 4; ++j)
      acc[i][j] = (f32x4){0.f, 0.f, 0.f, 0.f};

  const ushort* gA = A + (row0 + wave * 32 + lr) * 256 + lc * 8;
  const ushort* gB = Bt + ((long long)(col0 + wave * 32 + lr)) * 256 + lc * 8;
  ushort* lA = As + wave * 2048;
  ushort* lB = Bs + wave * 2048;

  #pragma unroll
  for (int kt = 0; kt < 4; ++kt){
    #pragma unroll
    for (int i = 0; i < 4; ++i){
      __builtin_amdgcn_global_load_lds(
          (const __attribute__((address_space(1))) void*)(gA + kt * 64 + i * 8 * 256),
          (__attribute__((address_space(3))) void*)(lA + i * 512), 16, 0, 0);
      __builtin_amdgcn_global_load_lds(
          (const __attribute__((address_space(1))) void*)(gB + kt * 64 + i * 8 * 256),
          (__attribute__((address_space(3))) void*)(lB + i * 512), 16, 0, 0);
    }
    __syncthreads();
    #pragma unroll
    for (int ks = 0; ks < 2; ++ks){
      const int kb = ks * 32 + ((lane >> 4) << 3);
      short8 af[4], bfv[4];
      #pragma unroll
      for (int i = 0; i < 4; ++i) af[i] = *(const short8*)(As + (mrow + i * 16) * 64 + kb);
      #pragma unroll
      for (int j = 0; j < 4; ++j) bfv[j] = *(const short8*)(Bs + (ncol + j * 16) * 64 + kb);
      #pragma unroll
      for (int i = 0; i < 4; ++i)
        #pragma unroll
        for (int j = 0; j < 4; ++j)
          acc[i][j] = __builtin_amdgcn_mfma_f32_16x16x32_bf16(af[i], bfv[j], acc[i][j], 0, 0, 0);
    }
    __syncthreads();
  }

  const int rbase = ((wave & 1) << 6) + ((lane >> 4) << 2);
  const int cb = col0 + ((wave >> 1) << 6) + (lane & 15);
  #pragma unroll
  for (int i = 0; i < 4; ++i)
    #pragma unroll
    for (int j = 0; j < 4; ++j)
      #pragma unroll
      for (int r = 0; r < 4; ++r){
        long long row = row0 + rbase + i * 16 + r;
        C[row * Nc + cb + j * 16] = f2bf(acc[i][j][r]);
      }
}

// ---------------- aggregation 1: width 256, wave per node ----------------
__global__ __launch_bounds__(64) void k_agg1(const ushort* __restrict__ h, const int* __restrict__ rs,
    const int* __restrict__ csrc, const float* __restrict__ dinv, const float* __restrict__ b1,
    float* __restrict__ h1){
  int n = blockIdx.x;
  int t = threadIdx.x;
  const ushort4* hv = (const ushort4*)h;
  float dn = dinv[n];
  ushort4 sv = hv[(long long)n * 64 + t];
  float a0 = dn * bf2f(sv.x), a1 = dn * bf2f(sv.y), a2 = dn * bf2f(sv.z), a3 = dn * bf2f(sv.w);
  int e = rs[n], end = rs[n + 1];
  for (; e < end; ++e){
    int s = csrc[e];
    float w = dinv[s];
    ushort4 v = hv[(long long)s * 64 + t];
    a0 += w * bf2f(v.x); a1 += w * bf2f(v.y); a2 += w * bf2f(v.z); a3 += w * bf2f(v.w);
  }
  float4 bb = ((const float4*)b1)[t];
  float4 r;
  r.x = dn * a0 + bb.x; r.y = dn * a1 + bb.y; r.z = dn * a2 + bb.z; r.w = dn * a3 + bb.w;
  ((float4*)h1)[(long long)n * 64 + t] = r;
}

// ---------------- aggregation 2: width 128, wave per node, fp32 out ----------------
__global__ __launch_bounds__(64) void k_agg2(const ushort* __restrict__ h2, const int* __restrict__ rs,
    const int* __restrict__ csrc, const float* __restrict__ dinv, const float* __restrict__ b2,
    float* __restrict__ out){
  int n = blockIdx.x;
  int t = threadIdx.x;
  const uint* hv = (const uint*)h2;
  float dn = dinv[n];
  uint sv = hv[(long long)n * 64 + t];
  float a0 = dn * bf2f((unsigned short)(sv & 0xFFFF));
  float a1 = dn * bf2f((unsigned short)(sv >> 16));
  int e = rs[n], end = rs[n + 1];
  for (; e < end; ++e){
    int s = csrc[e];
    float w = dinv[s];
    uint v = hv[(long long)s * 64 + t];
    a0 += w * bf2f((unsigned short)(v & 0xFFFF));
    a1 += w * bf2f((unsigned short)(v >> 16));
  }
  float2 bb = ((const float2*)b2)[t];
  float2 r; r.x = dn * a0 + bb.x; r.y = dn * a1 + bb.y;
  ((float2*)out)[(long long)n * 64 + t] = r;
}

// ---------------- BatchNorm ----------------
__global__ void k_bnstats(const float* __restrict__ h1, float* __restrict__ sums,
                          float* __restrict__ sqs, int N){
  int t = threadIdx.x;                 // column
  float s = 0.f, q = 0.f;
  for (int r = blockIdx.x; r < N; r += gridDim.x){
    float v = h1[(long long)r * 256 + t];
    s += v; q += v * v;
  }
  atomicAdd(&sums[t], s);
  atomicAdd(&sqs[t], q);
}

__global__ void k_bnfinal(const float* sums, const float* sqs, const float* gamma,
                          const float* beta, float* scale, float* shift, int N){
  int t = threadIdx.x;
  float inv = 1.0f / (float)N;
  float m = sums[t] * inv;
  float var = sqs[t] * inv - m * m;
  float sc = gamma[t] * rsqrtf(var + 1e-5f);
  scale[t] = sc;
  shift[t] = beta[t] - m * sc;
}

// BN apply + PReLU + bf16 cast (writes padded tail as zeros)
__global__ void k_prelu_bn(const float* __restrict__ h1, const float* __restrict__ scale,
                           const float* __restrict__ shift, const float* __restrict__ aP,
                           ushort* __restrict__ p, int N){
  int idx = blockIdx.x * blockDim.x + threadIdx.x;  // NP*128 (uint pairs)
  int row = idx >> 7, cp = idx & 127;
  uint o = 0;
  if (row < N){
    float2 v = ((const float2*)h1)[(long long)row * 128 + cp];
    int c0 = cp * 2;
    float aa = aP[0];
    float x0 = v.x * scale[c0] + shift[c0];
    float x1 = v.y * scale[c0 + 1] + shift[c0 + 1];
    x0 = x0 > 0.f ? x0 : aa * x0;
    x1 = x1 > 0.f ? x1 : aa * x1;
    o = (uint)f2bf(x0) | ((uint)f2bf(x1) << 16);
  }
  ((uint*)p)[idx] = o;
}

extern "C" void kernel_launch(void* const* d_in, const int* in_sizes, int n_in,
                              void* d_out, int out_size, void* d_ws, size_t ws_size,
                              hipStream_t stream){
  const float* x  = (const float*)d_in[0];
  const void*  ei = d_in[1];
  const float* W1 = (const float*)d_in[2];
  const float* b1 = (const float*)d_in[3];
  const float* W2 = (const float*)d_in[4];
  const float* b2 = (const float*)d_in[5];
  const float* gm = (const float*)d_in[6];
  const float* bt = (const float*)d_in[7];
  const float* aP = (const float*)d_in[8];
  float* out = (float*)d_out;

  const int N = in_sizes[0] / IN_DIM;          // 100000
  const long long E = in_sizes[1] / 2;         // 1600000
  const int NP = ((N + 127) / 128) * 128;      // 100096

  char* w = (char*)d_ws;
  size_t off = 0;
  auto carve = [&](size_t bytes) -> char* {
    char* p = w + off;
    off += (bytes + 255) & ~(size_t)255;
    return p;
  };
  ushort* xb  = (ushort*)carve((size_t)NP * 256 * 2);  // x bf16, later reused as p
  ushort* hb  = (ushort*)carve((size_t)NP * 256 * 2);  // h bf16, later reused as h2
  float*  h1  = (float*) carve((size_t)N * 256 * 4);
  ushort* W1t = (ushort*)carve(256 * 256 * 2);
  ushort* W2t = (ushort*)carve(128 * 256 * 2);
  int*   cnt  = (int*)  carve((size_t)N * 4);
  int*   rs   = (int*)  carve((size_t)(N + 1) * 4);
  int*   fill = (int*)  carve((size_t)N * 4);
  int*   csrc = (int*)  carve((size_t)E * 4);
  float* dinv = (float*)carve((size_t)N * 4);
  int*   bsum = (int*)  carve(512);
  int*   boff = (int*)  carve(512);
  float* sums = (float*)carve(1024);
  float* sqs  = (float*)carve(1024);
  float* scl  = (float*)carve(1024);
  float* shf  = (float*)carve(1024);
  int*   flag = (int*)  carve(256);

  const int NB1 = (N + 1023) / 1024;
  const int egrid = (int)((E + 255) / 256);

  k_detect<<<1, 256, 0, stream>>>(ei, E, N, flag);
  hipMemsetAsync(cnt, 0, (size_t)N * 4, stream);
  hipMemsetAsync(fill, 0, (size_t)N * 4, stream);
  hipMemsetAsync(sums, 0, 1024, stream);
  hipMemsetAsync(sqs, 0, 1024, stream);

  k_hist<<<egrid, 256, 0, stream>>>(ei, E, flag, cnt);
  k_dinv<<<(N + 255) / 256, 256, 0, stream>>>(cnt, dinv, N);
  k_scan1<<<NB1, 1024, 0, stream>>>(cnt, rs, bsum, N);
  k_scan2<<<1, 128, 0, stream>>>(bsum, boff, NB1, rs, N);
  k_scan3<<<NB1, 1024, 0, stream>>>(rs, boff, N);
  k_scatter<<<egrid, 256, 0, stream>>>(ei, E, flag, rs, fill, csrc);

  k_convx<<<NP / 4, 256, 0, stream>>>(x, xb, N);
  k_convw<<<256 * 256 / 256, 256, 0, stream>>>(W1, W1t, 256, 256);
  k_convw<<<128 * 256 / 256, 256, 0, stream>>>(W2, W2t, 256, 128);

  k_gemm<<<dim3(NP / 128, 2), 256, 0, stream>>>(xb, W1t, hb, 256);
  k_agg1<<<N, 64, 0, stream>>>(hb, rs, csrc, dinv, b1, h1);
  k_bnstats<<<256, 256, 0, stream>>>(h1, sums, sqs, N);
  k_bnfinal<<<1, 256, 0, stream>>>(sums, sqs, gm, bt, scl, shf, N);
  k_prelu_bn<<<NP / 2, 256, 0, stream>>>(h1, scl, shf, aP, xb, N);
  k_gemm<<<dim3(NP / 128, 1), 256, 0, stream>>>(xb, W2t, hb, 128);
  k_agg2<<<N, 64, 0, stream>>>(hb, rs, csrc, dinv, b2, out);
}

// Round 2
// 675.503 us; speedup vs baseline: 1.1143x; 1.1143x over previous
//
#include <hip/hip_runtime.h>
#include <hip/hip_bf16.h>
#include <stdint.h>

#define IN_DIM 256

typedef __attribute__((ext_vector_type(8))) short short8;
typedef __attribute__((ext_vector_type(4))) float f32x4;

__device__ __forceinline__ float bf2f(unsigned short u){
  return __uint_as_float(((unsigned int)u) << 16);
}
__device__ __forceinline__ unsigned short f2bf(float f){
  unsigned int u = __float_as_uint(f);
  u = u + 0x7FFFu + ((u >> 16) & 1u);
  return (unsigned short)(u >> 16);
}

// ---------------- edge dtype detection (int64 vs int32) ----------------
__global__ void k_detect(const void* ei, long long E, int N, int* flag){
  __shared__ int bad;
  if (threadIdx.x == 0) bad = 0;
  __syncthreads();
  const long long* p = (const long long*)ei;
  long long stride = E / 1024; if (stride < 1) stride = 1;
  for (int i = threadIdx.x; i < 1024; i += blockDim.x){
    long long idx = (long long)i * stride;
    if (idx >= E) break;
    long long v = p[idx];
    if (v < 0 || v >= (long long)N) atomicOr(&bad, 1);
  }
  __syncthreads();
  if (threadIdx.x == 0) flag[0] = bad ? 0 : 1;  // 1 = int64 data
}

__device__ __forceinline__ int edge_at(const void* ei, long long i, int f64){
  if (f64) return (int)((const long long*)ei)[i];
  return ((const int*)ei)[i];
}

// ---------------- CSR build ----------------
__global__ void k_hist(const void* ei, long long E, const int* flag, int* cnt){
  long long e = (long long)blockIdx.x * blockDim.x + threadIdx.x;
  if (e < E){
    int f = flag[0];
    int d = edge_at(ei, E + e, f);
    atomicAdd(&cnt[d], 1);
  }
}

// scan1 also produces dinv and zeroes fill
__global__ void k_scan1(const int* cnt, int* rs, int* bsum, float* dinv, int* fill, int N){
  __shared__ int sh[1024];
  int i = blockIdx.x * 1024 + threadIdx.x;
  int v = (i < N) ? cnt[i] : 0;
  sh[threadIdx.x] = v;
  __syncthreads();
  for (int o = 1; o < 1024; o <<= 1){
    int x = (threadIdx.x >= o) ? sh[threadIdx.x - o] : 0;
    __syncthreads();
    sh[threadIdx.x] += x;
    __syncthreads();
  }
  if (i < N){
    rs[i] = sh[threadIdx.x] - v;          // exclusive
    dinv[i] = rsqrtf((float)v + 1.0f);
    fill[i] = 0;
  }
  if (threadIdx.x == 1023) bsum[blockIdx.x] = sh[1023];
}

// scan2 also zeroes BN accumulators
__global__ void k_scan2(const int* bsum, int* boff, int nb, int* rs, int N,
                        float* sums, float* sqs){
  __shared__ int sh[128];
  int t = threadIdx.x;
  int v = (t < nb) ? bsum[t] : 0;
  sh[t] = v;
  __syncthreads();
  for (int o = 1; o < 128; o <<= 1){
    int x = (t >= o) ? sh[t - o] : 0;
    __syncthreads();
    sh[t] += x;
    __syncthreads();
  }
  boff[t] = sh[t] - v;
  if (t == 127) rs[N] = sh[127];
  sums[t] = 0.f; sums[t + 128] = 0.f;
  sqs[t]  = 0.f; sqs[t + 128]  = 0.f;
}

__global__ void k_scan3(int* rs, const int* boff, int N){
  int i = blockIdx.x * 1024 + threadIdx.x;
  if (i < N) rs[i] += boff[blockIdx.x];
}

__global__ void k_scatter(const void* ei, long long E, const int* flag, const int* rs,
                          int* fill, int* csrc){
  long long e = (long long)blockIdx.x * blockDim.x + threadIdx.x;
  if (e < E){
    int f = flag[0];
    int s = edge_at(ei, e, f);
    int d = edge_at(ei, E + e, f);
    int pos = atomicAdd(&fill[d], 1);
    csrc[rs[d] + pos] = s;
  }
}

// ---------------- fused conversions: xb=bf16(x), W1t, W2t transposed bf16 ----------------
__global__ void k_prep(const float* __restrict__ x, ushort* __restrict__ xb,
                       const float* __restrict__ W1, ushort* __restrict__ W1t,
                       const float* __restrict__ W2, ushort* __restrict__ W2t,
                       int N, int NP){
  int idx = blockIdx.x * 256 + threadIdx.x;
  int nxq = NP * 64;                        // ushort4 groups in xb
  if (idx < nxq){
    int row = idx >> 6, q = idx & 63;
    ushort4 o = {0, 0, 0, 0};
    if (row < N){
      float4 v = ((const float4*)x)[(size_t)row * 64 + q];
      o.x = f2bf(v.x); o.y = f2bf(v.y); o.z = f2bf(v.z); o.w = f2bf(v.w);
    }
    ((ushort4*)xb)[idx] = o;
  } else {
    int j = idx - nxq;
    if (j < 256 * 256){                     // W1t[n*256+k] = W1[k*256+n]
      int n = j >> 8, k = j & 255;
      W1t[j] = f2bf(W1[(size_t)k * 256 + n]);
    } else {
      j -= 65536;
      if (j < 128 * 256){                   // W2t[n*256+k] = W2[k*128+n]
        int n = j >> 8, k = j & 255;
        W2t[j] = f2bf(W2[(size_t)k * 128 + n]);
      }
    }
  }
}

// ---------------- GEMM: C[M,Nc] = dinv[row] * (A[M,256] @ Bt[Nc,256]^T)  bf16 out ----------------
__global__ __launch_bounds__(256) void k_gemm(const ushort* __restrict__ A,
                                              const ushort* __restrict__ Bt,
                                              ushort* __restrict__ C,
                                              const float* __restrict__ dinv,
                                              int N, int Nc){
  __shared__ ushort As[128 * 64];
  __shared__ ushort Bs[128 * 64];
  const int tid = threadIdx.x;
  const int wave = tid >> 6, lane = tid & 63;
  const long long row0 = (long long)blockIdx.x * 128;
  const int col0 = blockIdx.y * 128;
  const int lr = lane >> 3, lc = lane & 7;
  const int mrow = ((wave & 1) << 6) + (lane & 15);
  const int ncol = ((wave >> 1) << 6) + (lane & 15);

  f32x4 acc[4][4];
  #pragma unroll
  for (int i = 0; i < 4; ++i)
    #pragma unroll
    for (int j = 0; j < 4; ++j)
      acc[i][j] = (f32x4){0.f, 0.f, 0.f, 0.f};

  const ushort* gA = A + (row0 + wave * 32 + lr) * 256 + lc * 8;
  const ushort* gB = Bt + ((long long)(col0 + wave * 32 + lr)) * 256 + lc * 8;
  ushort* lA = As + wave * 2048;
  ushort* lB = Bs + wave * 2048;

  #pragma unroll
  for (int kt = 0; kt < 4; ++kt){
    #pragma unroll
    for (int i = 0; i < 4; ++i){
      __builtin_amdgcn_global_load_lds(
          (const __attribute__((address_space(1))) void*)(gA + kt * 64 + i * 8 * 256),
          (__attribute__((address_space(3))) void*)(lA + i * 512), 16, 0, 0);
      __builtin_amdgcn_global_load_lds(
          (const __attribute__((address_space(1))) void*)(gB + kt * 64 + i * 8 * 256),
          (__attribute__((address_space(3))) void*)(lB + i * 512), 16, 0, 0);
    }
    __syncthreads();
    #pragma unroll
    for (int ks = 0; ks < 2; ++ks){
      const int kb = ks * 32 + ((lane >> 4) << 3);
      short8 af[4], bfv[4];
      #pragma unroll
      for (int i = 0; i < 4; ++i) af[i] = *(const short8*)(As + (mrow + i * 16) * 64 + kb);
      #pragma unroll
      for (int j = 0; j < 4; ++j) bfv[j] = *(const short8*)(Bs + (ncol + j * 16) * 64 + kb);
      #pragma unroll
      for (int i = 0; i < 4; ++i)
        #pragma unroll
        for (int j = 0; j < 4; ++j)
          acc[i][j] = __builtin_amdgcn_mfma_f32_16x16x32_bf16(af[i], bfv[j], acc[i][j], 0, 0, 0);
    }
    __syncthreads();
  }

  const int rbase = ((wave & 1) << 6) + ((lane >> 4) << 2);
  const int cb = col0 + ((wave >> 1) << 6) + (lane & 15);
  #pragma unroll
  for (int i = 0; i < 4; ++i)
    #pragma unroll
    for (int r = 0; r < 4; ++r){
      long long row = row0 + rbase + i * 16 + r;
      float sc = (row < N) ? dinv[row] : 0.f;
      #pragma unroll
      for (int j = 0; j < 4; ++j)
        C[row * Nc + cb + j * 16] = f2bf(sc * acc[i][j][r]);
    }
}

// ---------------- aggregation 1: width 256, wave per node, pure row-sum, bf16 out ----------------
__global__ __launch_bounds__(64) void k_agg1(const ushort* __restrict__ hs, const int* __restrict__ rs,
    const int* __restrict__ csrc, const float* __restrict__ dinv, const float* __restrict__ b1,
    ushort* __restrict__ h1){
  int n = blockIdx.x;
  int t = threadIdx.x;
  const ushort4* hv = (const ushort4*)hs;
  ushort4 sv = hv[(size_t)n * 64 + t];
  float a0 = bf2f(sv.x), a1 = bf2f(sv.y), a2 = bf2f(sv.z), a3 = bf2f(sv.w);
  int e = rs[n], end = rs[n + 1];
  for (; e + 4 <= end; e += 4){
    int s0 = csrc[e], s1 = csrc[e + 1], s2 = csrc[e + 2], s3 = csrc[e + 3];
    ushort4 v0 = hv[(size_t)s0 * 64 + t];
    ushort4 v1 = hv[(size_t)s1 * 64 + t];
    ushort4 v2 = hv[(size_t)s2 * 64 + t];
    ushort4 v3 = hv[(size_t)s3 * 64 + t];
    a0 += bf2f(v0.x) + bf2f(v1.x) + bf2f(v2.x) + bf2f(v3.x);
    a1 += bf2f(v0.y) + bf2f(v1.y) + bf2f(v2.y) + bf2f(v3.y);
    a2 += bf2f(v0.z) + bf2f(v1.z) + bf2f(v2.z) + bf2f(v3.z);
    a3 += bf2f(v0.w) + bf2f(v1.w) + bf2f(v2.w) + bf2f(v3.w);
  }
  for (; e < end; ++e){
    int s = csrc[e];
    ushort4 v = hv[(size_t)s * 64 + t];
    a0 += bf2f(v.x); a1 += bf2f(v.y); a2 += bf2f(v.z); a3 += bf2f(v.w);
  }
  float dn = dinv[n];
  float4 bb = ((const float4*)b1)[t];
  ushort4 o;
  o.x = f2bf(dn * a0 + bb.x);
  o.y = f2bf(dn * a1 + bb.y);
  o.z = f2bf(dn * a2 + bb.z);
  o.w = f2bf(dn * a3 + bb.w);
  ((ushort4*)h1)[(size_t)n * 64 + t] = o;
}

// ---------------- aggregation 2: width 128, wave per node, fp32 out ----------------
__global__ __launch_bounds__(64) void k_agg2(const ushort* __restrict__ h2, const int* __restrict__ rs,
    const int* __restrict__ csrc, const float* __restrict__ dinv, const float* __restrict__ b2,
    float* __restrict__ out){
  int n = blockIdx.x;
  int t = threadIdx.x;
  const uint* hv = (const uint*)h2;
  uint sv = hv[(size_t)n * 64 + t];
  float a0 = bf2f((unsigned short)(sv & 0xFFFF));
  float a1 = bf2f((unsigned short)(sv >> 16));
  int e = rs[n], end = rs[n + 1];
  for (; e + 4 <= end; e += 4){
    int s0 = csrc[e], s1 = csrc[e + 1], s2 = csrc[e + 2], s3 = csrc[e + 3];
    uint v0 = hv[(size_t)s0 * 64 + t];
    uint v1 = hv[(size_t)s1 * 64 + t];
    uint v2 = hv[(size_t)s2 * 64 + t];
    uint v3 = hv[(size_t)s3 * 64 + t];
    a0 += bf2f((unsigned short)(v0 & 0xFFFF)) + bf2f((unsigned short)(v1 & 0xFFFF))
        + bf2f((unsigned short)(v2 & 0xFFFF)) + bf2f((unsigned short)(v3 & 0xFFFF));
    a1 += bf2f((unsigned short)(v0 >> 16)) + bf2f((unsigned short)(v1 >> 16))
        + bf2f((unsigned short)(v2 >> 16)) + bf2f((unsigned short)(v3 >> 16));
  }
  for (; e < end; ++e){
    int s = csrc[e];
    uint v = hv[(size_t)s * 64 + t];
    a0 += bf2f((unsigned short)(v & 0xFFFF));
    a1 += bf2f((unsigned short)(v >> 16));
  }
  float dn = dinv[n];
  float2 bb = ((const float2*)b2)[t];
  float2 r; r.x = dn * a0 + bb.x; r.y = dn * a1 + bb.y;
  ((float2*)out)[(size_t)n * 64 + t] = r;
}

// ---------------- BatchNorm stats from bf16 h1 ----------------
__global__ void k_bnstats(const ushort* __restrict__ h1, float* __restrict__ sums,
                          float* __restrict__ sqs, int N){
  int cp = threadIdx.x & 127, ro = threadIdx.x >> 7;   // column pair, row half
  const uint* hv = (const uint*)h1;
  float s0 = 0.f, s1 = 0.f, q0 = 0.f, q1 = 0.f;
  for (int r = blockIdx.x * 2 + ro; r < N; r += gridDim.x * 2){
    uint v = hv[(size_t)r * 128 + cp];
    float x0 = bf2f((unsigned short)(v & 0xFFFF));
    float x1 = bf2f((unsigned short)(v >> 16));
    s0 += x0; q0 += x0 * x0;
    s1 += x1; q1 += x1 * x1;
  }
  atomicAdd(&sums[2 * cp],     s0);
  atomicAdd(&sums[2 * cp + 1], s1);
  atomicAdd(&sqs[2 * cp],      q0);
  atomicAdd(&sqs[2 * cp + 1],  q1);
}

// ---------------- BN finalize + apply + PReLU + bf16 cast ----------------
__global__ void k_prelu(const ushort* __restrict__ h1, const float* __restrict__ sums,
                        const float* __restrict__ sqs, const float* __restrict__ gamma,
                        const float* __restrict__ beta, const float* __restrict__ aP,
                        ushort* __restrict__ P, int N, int NP){
  int idx = blockIdx.x * 256 + threadIdx.x;   // NP*128 uint pairs
  int row = idx >> 7, cp = idx & 127;
  if (row >= NP) return;
  uint o = 0;
  if (row < N){
    int c0 = 2 * cp;
    float inv = 1.0f / (float)N;
    float m0 = sums[c0] * inv,     m1 = sums[c0 + 1] * inv;
    float v0 = sqs[c0] * inv - m0 * m0, v1 = sqs[c0 + 1] * inv - m1 * m1;
    float sc0 = gamma[c0] * rsqrtf(v0 + 1e-5f);
    float sc1 = gamma[c0 + 1] * rsqrtf(v1 + 1e-5f);
    float sh0 = beta[c0] - m0 * sc0;
    float sh1 = beta[c0 + 1] - m1 * sc1;
    uint v = ((const uint*)h1)[(size_t)row * 128 + cp];
    float aa = aP[0];
    float x0 = bf2f((unsigned short)(v & 0xFFFF)) * sc0 + sh0;
    float x1 = bf2f((unsigned short)(v >> 16)) * sc1 + sh1;
    x0 = x0 > 0.f ? x0 : aa * x0;
    x1 = x1 > 0.f ? x1 : aa * x1;
    o = (uint)f2bf(x0) | ((uint)f2bf(x1) << 16);
  }
  ((uint*)P)[idx] = o;
}

extern "C" void kernel_launch(void* const* d_in, const int* in_sizes, int n_in,
                              void* d_out, int out_size, void* d_ws, size_t ws_size,
                              hipStream_t stream){
  const float* x  = (const float*)d_in[0];
  const void*  ei = d_in[1];
  const float* W1 = (const float*)d_in[2];
  const float* b1 = (const float*)d_in[3];
  const float* W2 = (const float*)d_in[4];
  const float* b2 = (const float*)d_in[5];
  const float* gm = (const float*)d_in[6];
  const float* bt = (const float*)d_in[7];
  const float* aP = (const float*)d_in[8];
  float* out = (float*)d_out;

  const int N = in_sizes[0] / IN_DIM;          // 100000
  const long long E = in_sizes[1] / 2;         // 1600000
  const int NP = ((N + 127) / 128) * 128;      // 100096

  char* w = (char*)d_ws;
  size_t off = 0;
  auto carve = [&](size_t bytes) -> char* {
    char* p = w + off;
    off += (bytes + 255) & ~(size_t)255;
    return p;
  };
  ushort* xb  = (ushort*)carve((size_t)NP * 256 * 2);  // x bf16; reused for P
  ushort* hb  = (ushort*)carve((size_t)NP * 256 * 2);  // hs bf16; reused for h2s
  ushort* h1b = (ushort*)carve((size_t)NP * 256 * 2);  // h1 bf16
  ushort* W1t = (ushort*)carve(256 * 256 * 2);
  ushort* W2t = (ushort*)carve(128 * 256 * 2);
  int*   cnt  = (int*)  carve((size_t)N * 4);
  int*   rs   = (int*)  carve((size_t)(N + 1) * 4);
  int*   fill = (int*)  carve((size_t)N * 4);
  int*   csrc = (int*)  carve((size_t)E * 4);
  float* dinv = (float*)carve((size_t)N * 4);
  int*   bsum = (int*)  carve(512);
  int*   boff = (int*)  carve(512);
  float* sums = (float*)carve(1024);
  float* sqs  = (float*)carve(1024);
  int*   flag = (int*)  carve(256);

  const int NB1 = (N + 1023) / 1024;
  const int egrid = (int)((E + 255) / 256);
  const int prep_grid = (NP * 64 + 256 * 256 + 128 * 256 + 255) / 256;

  k_detect<<<1, 256, 0, stream>>>(ei, E, N, flag);
  hipMemsetAsync(cnt, 0, (size_t)N * 4, stream);
  k_prep<<<prep_grid, 256, 0, stream>>>(x, xb, W1, W1t, W2, W2t, N, NP);
  k_hist<<<egrid, 256, 0, stream>>>(ei, E, flag, cnt);
  k_scan1<<<NB1, 1024, 0, stream>>>(cnt, rs, bsum, dinv, fill, N);
  k_scan2<<<1, 128, 0, stream>>>(bsum, boff, NB1, rs, N, sums, sqs);
  k_scan3<<<NB1, 1024, 0, stream>>>(rs, boff, N);
  k_scatter<<<egrid, 256, 0, stream>>>(ei, E, flag, rs, fill, csrc);

  k_gemm<<<dim3(NP / 128, 2), 256, 0, stream>>>(xb, W1t, hb, dinv, N, 256);
  k_agg1<<<N, 64, 0, stream>>>(hb, rs, csrc, dinv, b1, h1b);
  k_bnstats<<<256, 256, 0, stream>>>(h1b, sums, sqs, N);
  k_prelu<<<(NP * 128 + 255) / 256, 256, 0, stream>>>(h1b, sums, sqs, gm, bt, aP, xb, N, NP);
  k_gemm<<<dim3(NP / 128, 1), 256, 0, stream>>>(xb, W2t, hb, dinv, N, 128);
  k_agg2<<<N, 64, 0, stream>>>(hb, rs, csrc, dinv, b2, out);
}